// Round 4
// baseline (337.339 us; speedup 1.0000x reference)
//
#include <hip/hip_runtime.h>
#include <hip/hip_bf16.h>

// VirtualTextureModule: trilinear mip-mapped texture sampling.
// data [1,4096,4096,3] f32, texc [1,1024,1024,2] f32, texc_deriv [1,1024,1024,4] f32
// out  [1,1024,1024,3] f32
//
// R8.1 (resubmit of R8; previous bench failed on container acquisition, not kernel):
//  - mip_l2: block = 4 raw rows x 1024 cols -> four 12 KB CONTIGUOUS runs
//    staged to LDS via global_load_lds w=16 (compile-time row/chunk mapping).
//    One thread = one L2 texel. Stores L2 packed u32 (linear) + fp32 float4
//    copy at FOFF (preserves full-precision ladder numerics).
//  - mip_rest: 1024 blocks; L3..L6 from the fp32 L2 copy via LDS ladder
//    (identical numerics to R7's in-block ladder). ~5 us.
//  - sampler: LINEAR level layout (offset = (y*size + x)*4), same 8 taps.
//    lod<2 (~1.3%) on-the-fly from data; lod>6 (~1e-7) from stored L6.

#define OUT_N (1024 * 1024)

__device__ __forceinline__ unsigned mip_off_b(int lvl) {
    return (67108864u - (67108864u >> (2 * lvl - 2))) / 3u;
}
#define OFF2 16777216u
#define OFF3 20971520u
#define OFF4 22020096u
#define OFF5 22282240u
#define OFF6 22347776u
#define FOFF 25165824u   // fp32 float4 L2 copy: [24 MB, 40 MB)

__device__ __forceinline__ unsigned pack10(float r, float g, float b) {
    unsigned ur = __float2uint_rn(r * 1023.0f);
    unsigned ug = __float2uint_rn(g * 1023.0f);
    unsigned ub = __float2uint_rn(b * 1023.0f);
    return ur | (ug << 10) | (ub << 20);
}

__device__ __forceinline__ void dec_acc(unsigned q, float w, float& r, float& g, float& b) {
    const float s = 1.0f / 1023.0f;
    r = fmaf((float)(q & 1023u) * s, w, r);
    g = fmaf((float)((q >> 10) & 1023u) * s, w, g);
    b = fmaf((float)((q >> 20) & 1023u) * s, w, b);
}

__device__ __forceinline__ float4 dec4(unsigned q) {
    const float s = 1.0f / 1023.0f;
    return float4{(float)(q & 1023u) * s, (float)((q >> 10) & 1023u) * s,
                  (float)((q >> 20) & 1023u) * s, 0.0f};
}

__device__ __forceinline__ float4 avg4(float4 a, float4 b, float4 c, float4 d) {
    return float4{(a.x + b.x + c.x + d.x) * 0.25f,
                  (a.y + b.y + c.y + d.y) * 0.25f,
                  (a.z + b.z + c.z + d.z) * 0.25f, 0.0f};
}

// ---------------- kernel A: L2 build (pure streaming) ----------------
// Block = raw rows [4*l2row, 4*l2row+4), cols [1024*c4, 1024*(c4+1)).
// Each raw row chunk = 12 KB contiguous. LDS = 4 x 12 KB linear.
__global__ __launch_bounds__(256) void mip_l2(const float* __restrict__ data,
                                              char* __restrict__ wsb) {
    __shared__ float4 tile[3072];          // 48 KB
    const int t = threadIdx.x;
    const unsigned b = blockIdx.x;
    const unsigned l2row = b >> 2;         // 0..1023
    const unsigned c4 = b & 3;             // col-block 0..3
    const char* src = (const char*)data + (size_t)l2row * 4 * 49152 + (size_t)c4 * 12288;
    char* lds = (char*)tile;

#pragma unroll
    for (int r = 0; r < 4; ++r) {
#pragma unroll
        for (int k = 0; k < 3; ++k) {
            unsigned fo = (unsigned)(k * 256 + t);      // float4 idx within row
            __builtin_amdgcn_global_load_lds(
                (const __attribute__((address_space(1))) unsigned int*)
                    (src + (size_t)r * 49152 + (size_t)fo * 16),
                (__attribute__((address_space(3))) unsigned int*)
                    (lds + ((size_t)r * 768 + fo) * 16),
                16, 0, 0);
        }
    }
    __syncthreads();

    // one L2 texel per thread: 4x4 raw box at col 4*t (bytes 48*t .. 48*t+48)
    float rr = 0.0f, gg = 0.0f, bb = 0.0f;
#pragma unroll
    for (int i = 0; i < 4; ++i) {
        const float4* rp = (const float4*)(lds + (size_t)i * 12288 + (size_t)t * 48);
        float4 A = rp[0], Bv = rp[1], Cv = rp[2];
        // texels: (A.x,A.y,A.z)(A.w,Bv.x,Bv.y)(Bv.z,Bv.w,Cv.x)(Cv.y,Cv.z,Cv.w)
        rr += A.x + A.w + Bv.z + Cv.y;
        gg += A.y + Bv.x + Bv.w + Cv.z;
        bb += A.z + Bv.y + Cv.x + Cv.w;
    }
    const float sc = 1.0f / 16.0f;
    rr *= sc; gg *= sc; bb *= sc;

    size_t idx = ((size_t)l2row << 10) + ((size_t)c4 << 8) + (size_t)t;
    *(unsigned*)(wsb + OFF2 + idx * 4) = pack10(rr, gg, bb);         // packed (sampler)
    *(float4*)(wsb + FOFF + idx * 16) = float4{rr, gg, bb, 0.0f};    // fp32 (ladder)
}

// ---------------- kernel B: L3..L6 from fp32 L2 copy ----------------
// Block = 32x32 L2 region (16x16 L3). 1024 blocks.
__global__ __launch_bounds__(256) void mip_rest(char* __restrict__ wsb) {
    __shared__ float4 s3[16][17];
    __shared__ float4 s4[8][9];
    __shared__ float4 s5[4][5];
    const int t = threadIdx.x;
    const unsigned bby = blockIdx.x >> 5;   // 0..31
    const unsigned bbx = blockIdx.x & 31;

    {   // L3: one texel per thread
        int tx = t & 15, ty = t >> 4;
        unsigned R3 = (bby << 4) + ty;      // 0..511
        unsigned C3 = (bbx << 4) + tx;
        const char* F = wsb + FOFF;
        const float4* p0 = (const float4*)(F + ((((size_t)R3 * 2) << 10) + (size_t)C3 * 2) * 16);
        const float4* p1 = (const float4*)(F + ((((size_t)R3 * 2 + 1) << 10) + (size_t)C3 * 2) * 16);
        float4 v = avg4(p0[0], p0[1], p1[0], p1[1]);
        s3[ty][tx] = v;
        *(unsigned*)(wsb + OFF3 + (((size_t)R3 << 9) + C3) * 4) = pack10(v.x, v.y, v.z);
    }
    __syncthreads();

    if (t < 64) {   // L4
        int tx = t & 7, ty = t >> 3;
        float4 v = avg4(s3[2 * ty][2 * tx], s3[2 * ty][2 * tx + 1],
                        s3[2 * ty + 1][2 * tx], s3[2 * ty + 1][2 * tx + 1]);
        s4[ty][tx] = v;
        unsigned R4 = (bby << 3) + ty, C4 = (bbx << 3) + tx;   // 0..255
        *(unsigned*)(wsb + OFF4 + (((size_t)R4 << 8) + C4) * 4) = pack10(v.x, v.y, v.z);
    }
    __syncthreads();

    if (t < 16) {   // L5
        int tx = t & 3, ty = t >> 2;
        float4 v = avg4(s4[2 * ty][2 * tx], s4[2 * ty][2 * tx + 1],
                        s4[2 * ty + 1][2 * tx], s4[2 * ty + 1][2 * tx + 1]);
        s5[ty][tx] = v;
        unsigned R5 = (bby << 2) + ty, C5 = (bbx << 2) + tx;   // 0..127
        *(unsigned*)(wsb + OFF5 + (((size_t)R5 << 7) + C5) * 4) = pack10(v.x, v.y, v.z);
    }
    __syncthreads();

    if (t < 4) {    // L6
        int tx = t & 1, ty = t >> 1;
        float4 v = avg4(s5[2 * ty][2 * tx], s5[2 * ty][2 * tx + 1],
                        s5[2 * ty + 1][2 * tx], s5[2 * ty + 1][2 * tx + 1]);
        unsigned R6r = (bby << 1) + ty, C6 = (bbx << 1) + tx;  // 0..63
        *(unsigned*)(wsb + OFF6 + (((size_t)R6r << 6) + C6) * 4) = pack10(v.x, v.y, v.z);
    }
}

// ---------------- sampling (linear level layout) ----------------
__device__ __forceinline__ void tap_off(int lvl, float u, float v,
                                        unsigned& o00, unsigned& o01,
                                        unsigned& o10, unsigned& o11,
                                        float& fx, float& fy) {
    int size = 4096 >> lvl;
    float fs = (float)size;
    float x = fmaf(u, fs, -0.5f);
    float y = fmaf(v, fs, -0.5f);
    float x0f = floorf(x);
    float y0f = floorf(y);
    fx = x - x0f;
    fy = y - y0f;
    int m = size - 1;
    unsigned x0 = (unsigned)(((int)x0f) & m);
    unsigned y0 = (unsigned)(((int)y0f) & m);
    unsigned x1 = (x0 + 1) & (unsigned)m;
    unsigned y1 = (y0 + 1) & (unsigned)m;
    int sh = 12 - lvl;                       // y*size == y << sh
    unsigned r0 = y0 << sh, r1 = y1 << sh;
    o00 = (r0 + x0) << 2;
    o01 = (r0 + x1) << 2;
    o10 = (r1 + x0) << 2;
    o11 = (r1 + x1) << 2;
}

__device__ __forceinline__ void sample_packed(const char* __restrict__ wsb, int lvl,
                                              float u, float v, float wgt,
                                              float& r, float& g, float& b) {
    unsigned o00, o01, o10, o11;
    float fx, fy;
    tap_off(lvl, u, v, o00, o01, o10, o11, fx, fy);
    const char* B = wsb + mip_off_b(lvl);
    unsigned q00 = *(const unsigned*)(B + o00);
    unsigned q01 = *(const unsigned*)(B + o01);
    unsigned q10 = *(const unsigned*)(B + o10);
    unsigned q11 = *(const unsigned*)(B + o11);
    dec_acc(q00, (1.0f - fx) * (1.0f - fy) * wgt, r, g, b);
    dec_acc(q01, fx * (1.0f - fy) * wgt, r, g, b);
    dec_acc(q10, (1.0f - fx) * fy * wgt, r, g, b);
    dec_acc(q11, fx * fy * wgt, r, g, b);
}

// Rare path (lod < 2, ~1.3%): levels 0..1 on the fly from fp32 data.
__device__ void sample_fine(const float* __restrict__ data, int lvl,
                            float u, float v, float wgt,
                            float& r, float& g, float& b) {
    int size = 4096 >> lvl;
    float fs = (float)size;
    float x = u * fs - 0.5f;
    float y = v * fs - 0.5f;
    float x0f = floorf(x);
    float y0f = floorf(y);
    float fx = x - x0f;
    float fy = y - y0f;
    int m = size - 1;
    int x0 = ((int)x0f) & m;
    int y0 = ((int)y0f) & m;
    int x1 = (x0 + 1) & m;
    int y1 = (y0 + 1) & m;
    int k = 1 << lvl;
    float inv = wgt / (float)(k * k);
    float ww[2][2] = {{(1.0f - fx) * (1.0f - fy) * inv, fx * (1.0f - fy) * inv},
                      {(1.0f - fx) * fy * inv, fx * fy * inv}};
    int xs[2] = {x0 << lvl, x1 << lvl};
    int ys[2] = {y0 << lvl, y1 << lvl};
    for (int ty = 0; ty < 2; ++ty)
        for (int tx = 0; tx < 2; ++tx) {
            float tr = 0.0f, tg = 0.0f, tb = 0.0f;
            for (int dy = 0; dy < k; ++dy)
                for (int dx = 0; dx < k; ++dx) {
                    const float* p = data + ((size_t)(ys[ty] + dy) * 4096 + xs[tx] + dx) * 3;
                    tr += p[0]; tg += p[1]; tb += p[2];
                }
            r = fmaf(tr, ww[ty][tx], r);
            g = fmaf(tg, ww[ty][tx], g);
            b = fmaf(tb, ww[ty][tx], b);
        }
}

// Near-never path (lod > 6, P ~ 1e-7): levels 7..8 on the fly from stored L6.
__device__ float4 read_l6(const char* __restrict__ wsb, int xx, int yy) {
    return dec4(*(const unsigned*)(wsb + OFF6 + ((((size_t)yy << 6) + xx) << 2)));
}

__device__ void sample_coarse(const char* __restrict__ wsb, int lvl,
                              float u, float v, float wgt,
                              float& r, float& g, float& b) {
    int size = 4096 >> lvl;          // 32 (l=7) or 16 (l=8)
    float fs = (float)size;
    float x = u * fs - 0.5f;
    float y = v * fs - 0.5f;
    float x0f = floorf(x);
    float y0f = floorf(y);
    float fx = x - x0f;
    float fy = y - y0f;
    int m = size - 1;
    int x0 = ((int)x0f) & m;
    int y0 = ((int)y0f) & m;
    int x1 = (x0 + 1) & m;
    int y1 = (y0 + 1) & m;
    int s = lvl - 6;
    int k = 1 << s;
    float inv = wgt / (float)(k * k);
    float ww[2][2] = {{(1.0f - fx) * (1.0f - fy) * inv, fx * (1.0f - fy) * inv},
                      {(1.0f - fx) * fy * inv, fx * fy * inv}};
    int xs[2] = {x0 << s, x1 << s};
    int ys[2] = {y0 << s, y1 << s};
    for (int ty = 0; ty < 2; ++ty)
        for (int tx = 0; tx < 2; ++tx) {
            float tr = 0.0f, tg = 0.0f, tb = 0.0f;
            for (int dy = 0; dy < k; ++dy)
                for (int dx = 0; dx < k; ++dx) {
                    float4 c = read_l6(wsb, xs[tx] + dx, ys[ty] + dy);
                    tr += c.x; tg += c.y; tb += c.z;
                }
            r = fmaf(tr, ww[ty][tx], r);
            g = fmaf(tg, ww[ty][tx], g);
            b = fmaf(tb, ww[ty][tx], b);
        }
}

__device__ __forceinline__ void sample_any(const float* __restrict__ data,
                                           const char* __restrict__ wsb, int lvl,
                                           float u, float v, float wgt,
                                           float& r, float& g, float& b) {
    if (lvl >= 2) {
        if (lvl <= 6) sample_packed(wsb, lvl, u, v, wgt, r, g, b);
        else sample_coarse(wsb, lvl, u, v, wgt, r, g, b);            // ~never
    } else {
        sample_fine(data, lvl, u, v, wgt, r, g, b);                  // rare
    }
}

__global__ __launch_bounds__(256) void vt_sample(const float* __restrict__ data,
                                                 const char* __restrict__ wsb,
                                                 const float* __restrict__ texc,
                                                 const float* __restrict__ deriv,
                                                 float* __restrict__ out) {
    int p = blockIdx.x * 256 + threadIdx.x;

    float2 uv = ((const float2*)texc)[p];
    float4 dv = ((const float4*)deriv)[p];
    float dudx = dv.x * 4096.0f;
    float dvdx = dv.y * 4096.0f;
    float dudy = dv.z * 4096.0f;
    float dvdy = dv.w * 4096.0f;
    float rho2 = fmaxf(fmaf(dudx, dudx, dvdx * dvdx), fmaf(dudy, dudy, dvdy * dvdy));
    float lod = 0.5f * __log2f(fmaxf(rho2, 1e-20f));
    lod = fminf(fmaxf(lod, 0.0f), 8.0f);

    int l0 = (int)lod;            // trunc == floor for lod >= 0
    float f = lod - (float)l0;
    int l1 = (l0 < 8) ? (l0 + 1) : 8;

    float r = 0.0f, g = 0.0f, b = 0.0f;

    if (__builtin_expect((unsigned)(l0 - 2) <= 3u, 1)) {
        // Fused fast path: l0 in [2,5] -> both levels packed. Compute all 8
        // tap offsets, issue all 8 loads, THEN do the weight math (one wait).
        unsigned a00, a01, a10, a11, b00, b01, b10, b11;
        float fx0, fy0, fx1, fy1;
        const char* B0 = wsb + mip_off_b(l0);
        const char* B1 = wsb + mip_off_b(l1);
        tap_off(l0, uv.x, uv.y, a00, a01, a10, a11, fx0, fy0);
        tap_off(l1, uv.x, uv.y, b00, b01, b10, b11, fx1, fy1);
        unsigned q0 = *(const unsigned*)(B0 + a00);
        unsigned q1 = *(const unsigned*)(B0 + a01);
        unsigned q2 = *(const unsigned*)(B0 + a10);
        unsigned q3 = *(const unsigned*)(B0 + a11);
        unsigned q4 = *(const unsigned*)(B1 + b00);
        unsigned q5 = *(const unsigned*)(B1 + b01);
        unsigned q6 = *(const unsigned*)(B1 + b10);
        unsigned q7 = *(const unsigned*)(B1 + b11);
        float w0 = 1.0f - f;
        dec_acc(q0, (1.0f - fx0) * (1.0f - fy0) * w0, r, g, b);
        dec_acc(q1, fx0 * (1.0f - fy0) * w0, r, g, b);
        dec_acc(q2, (1.0f - fx0) * fy0 * w0, r, g, b);
        dec_acc(q3, fx0 * fy0 * w0, r, g, b);
        dec_acc(q4, (1.0f - fx1) * (1.0f - fy1) * f, r, g, b);
        dec_acc(q5, fx1 * (1.0f - fy1) * f, r, g, b);
        dec_acc(q6, (1.0f - fx1) * fy1 * f, r, g, b);
        dec_acc(q7, fx1 * fy1 * f, r, g, b);
    } else {
        sample_any(data, wsb, l0, uv.x, uv.y, 1.0f - f, r, g, b);
        sample_any(data, wsb, l1, uv.x, uv.y, f, r, g, b);
    }

    float* o = out + (size_t)p * 3;
    o[0] = r;
    o[1] = g;
    o[2] = b;
}

extern "C" void kernel_launch(void* const* d_in, const int* in_sizes, int n_in,
                              void* d_out, int out_size, void* d_ws, size_t ws_size,
                              hipStream_t stream) {
    const float* data  = (const float*)d_in[0];
    const float* texc  = (const float*)d_in[1];
    const float* deriv = (const float*)d_in[2];
    float* out = (float*)d_out;
    char* wsb  = (char*)d_ws;

    mip_l2<<<4096, 256, 0, stream>>>(data, wsb);
    mip_rest<<<1024, 256, 0, stream>>>(wsb);
    vt_sample<<<OUT_N / 256, 256, 0, stream>>>(data, wsb, texc, deriv, out);
}

// Round 5
// 336.329 us; speedup vs baseline: 1.0030x; 1.0030x over previous
//
#include <hip/hip_runtime.h>
#include <hip/hip_bf16.h>

// VirtualTextureModule: trilinear mip-mapped texture sampling.
// data [1,4096,4096,3] f32, texc [1,1024,1024,2] f32, texc_deriv [1,1024,1024,4] f32
// out  [1,1024,1024,3] f32
//
// R9 design (kill the stage/drain convoy):
//  - mip_l2: REGISTER-ONLY, barrier-free. One thread = one L2 texel.
//    Per raw row it loads 3 consecutive float4 (48 B/lane, lane stride 48 B
//    -> wave covers a contiguous 3 KB span, every 16-B sector used once:
//    no over-fetch). All 12 loads issued before any use (full MLP), no LDS,
//    no __syncthreads -> no vmcnt(0) drain convoy. Stores packed u32 L2 +
//    fp32 float4 copy at FOFF (full-precision ladder numerics preserved).
//  - mip_rest: 1024 blocks; L3..L6 from the fp32 L2 copy via LDS ladder.
//  - sampler: linear level layout, fused dual-level fast path (l0 in [2,5]);
//    lod<2 (~1.3%) on-the-fly from data; lod>6 (~1e-7) from stored L6.

#define OUT_N (1024 * 1024)

__device__ __forceinline__ unsigned mip_off_b(int lvl) {
    return (67108864u - (67108864u >> (2 * lvl - 2))) / 3u;
}
#define OFF2 16777216u
#define OFF3 20971520u
#define OFF4 22020096u
#define OFF5 22282240u
#define OFF6 22347776u
#define FOFF 25165824u   // fp32 float4 L2 copy: [24 MB, 40 MB)

__device__ __forceinline__ unsigned pack10(float r, float g, float b) {
    unsigned ur = __float2uint_rn(r * 1023.0f);
    unsigned ug = __float2uint_rn(g * 1023.0f);
    unsigned ub = __float2uint_rn(b * 1023.0f);
    return ur | (ug << 10) | (ub << 20);
}

__device__ __forceinline__ void dec_acc(unsigned q, float w, float& r, float& g, float& b) {
    const float s = 1.0f / 1023.0f;
    r = fmaf((float)(q & 1023u) * s, w, r);
    g = fmaf((float)((q >> 10) & 1023u) * s, w, g);
    b = fmaf((float)((q >> 20) & 1023u) * s, w, b);
}

__device__ __forceinline__ float4 dec4(unsigned q) {
    const float s = 1.0f / 1023.0f;
    return float4{(float)(q & 1023u) * s, (float)((q >> 10) & 1023u) * s,
                  (float)((q >> 20) & 1023u) * s, 0.0f};
}

__device__ __forceinline__ float4 avg4(float4 a, float4 b, float4 c, float4 d) {
    return float4{(a.x + b.x + c.x + d.x) * 0.25f,
                  (a.y + b.y + c.y + d.y) * 0.25f,
                  (a.z + b.z + c.z + d.z) * 0.25f, 0.0f};
}

// ---------------- kernel A: L2 build (register-only streaming) ----------
// Thread = L2 texel (l2row, x). Raw footprint: rows 4*l2row..+3, cols 4x..4x+3
// = 4 rows x 48 B, each row 3 consecutive float4. Block = one L2 row quarter.
__global__ __launch_bounds__(256) void mip_l2(const float* __restrict__ data,
                                              char* __restrict__ wsb) {
    const int t = threadIdx.x;
    const unsigned b = blockIdx.x;
    const unsigned l2row = b >> 2;         // 0..1023
    const unsigned x = ((b & 3) << 8) + (unsigned)t;   // L2 col 0..1023
    const char* src = (const char*)data + (size_t)l2row * 4 * 49152 + (size_t)x * 48;

    // issue all 12 loads first (full MLP), then reduce
    float4 v0, v1, v2, v3, v4, v5, v6, v7, v8, v9, v10, v11;
    {
        const float4* r0 = (const float4*)(src);
        const float4* r1 = (const float4*)(src + 49152);
        const float4* r2 = (const float4*)(src + 2 * 49152);
        const float4* r3 = (const float4*)(src + 3 * 49152);
        v0 = r0[0]; v1 = r0[1]; v2 = r0[2];
        v3 = r1[0]; v4 = r1[1]; v5 = r1[2];
        v6 = r2[0]; v7 = r2[1]; v8 = r2[2];
        v9 = r3[0]; v10 = r3[1]; v11 = r3[2];
    }
    // row texels: (A.x,A.y,A.z)(A.w,B.x,B.y)(B.z,B.w,C.x)(C.y,C.z,C.w)
    float rr = 0.0f, gg = 0.0f, bb = 0.0f;
    rr += v0.x + v0.w + v1.z + v2.y;  gg += v0.y + v1.x + v1.w + v2.z;  bb += v0.z + v1.y + v2.x + v2.w;
    rr += v3.x + v3.w + v4.z + v5.y;  gg += v3.y + v4.x + v4.w + v5.z;  bb += v3.z + v4.y + v5.x + v5.w;
    rr += v6.x + v6.w + v7.z + v8.y;  gg += v6.y + v7.x + v7.w + v8.z;  bb += v6.z + v7.y + v8.x + v8.w;
    rr += v9.x + v9.w + v10.z + v11.y; gg += v9.y + v10.x + v10.w + v11.z; bb += v9.z + v10.y + v11.x + v11.w;
    const float sc = 1.0f / 16.0f;
    rr *= sc; gg *= sc; bb *= sc;

    size_t idx = ((size_t)l2row << 10) + (size_t)x;
    *(unsigned*)(wsb + OFF2 + idx * 4) = pack10(rr, gg, bb);         // packed (sampler)
    *(float4*)(wsb + FOFF + idx * 16) = float4{rr, gg, bb, 0.0f};    // fp32 (ladder)
}

// ---------------- kernel B: L3..L6 from fp32 L2 copy ----------------
// Block = 32x32 L2 region (16x16 L3). 1024 blocks.
__global__ __launch_bounds__(256) void mip_rest(char* __restrict__ wsb) {
    __shared__ float4 s3[16][17];
    __shared__ float4 s4[8][9];
    __shared__ float4 s5[4][5];
    const int t = threadIdx.x;
    const unsigned bby = blockIdx.x >> 5;   // 0..31
    const unsigned bbx = blockIdx.x & 31;

    {   // L3: one texel per thread
        int tx = t & 15, ty = t >> 4;
        unsigned R3 = (bby << 4) + ty;      // 0..511
        unsigned C3 = (bbx << 4) + tx;
        const char* F = wsb + FOFF;
        const float4* p0 = (const float4*)(F + ((((size_t)R3 * 2) << 10) + (size_t)C3 * 2) * 16);
        const float4* p1 = (const float4*)(F + ((((size_t)R3 * 2 + 1) << 10) + (size_t)C3 * 2) * 16);
        float4 v = avg4(p0[0], p0[1], p1[0], p1[1]);
        s3[ty][tx] = v;
        *(unsigned*)(wsb + OFF3 + (((size_t)R3 << 9) + C3) * 4) = pack10(v.x, v.y, v.z);
    }
    __syncthreads();

    if (t < 64) {   // L4
        int tx = t & 7, ty = t >> 3;
        float4 v = avg4(s3[2 * ty][2 * tx], s3[2 * ty][2 * tx + 1],
                        s3[2 * ty + 1][2 * tx], s3[2 * ty + 1][2 * tx + 1]);
        s4[ty][tx] = v;
        unsigned R4 = (bby << 3) + ty, C4 = (bbx << 3) + tx;   // 0..255
        *(unsigned*)(wsb + OFF4 + (((size_t)R4 << 8) + C4) * 4) = pack10(v.x, v.y, v.z);
    }
    __syncthreads();

    if (t < 16) {   // L5
        int tx = t & 3, ty = t >> 2;
        float4 v = avg4(s4[2 * ty][2 * tx], s4[2 * ty][2 * tx + 1],
                        s4[2 * ty + 1][2 * tx], s4[2 * ty + 1][2 * tx + 1]);
        s5[ty][tx] = v;
        unsigned R5 = (bby << 2) + ty, C5 = (bbx << 2) + tx;   // 0..127
        *(unsigned*)(wsb + OFF5 + (((size_t)R5 << 7) + C5) * 4) = pack10(v.x, v.y, v.z);
    }
    __syncthreads();

    if (t < 4) {    // L6
        int tx = t & 1, ty = t >> 1;
        float4 v = avg4(s5[2 * ty][2 * tx], s5[2 * ty][2 * tx + 1],
                        s5[2 * ty + 1][2 * tx], s5[2 * ty + 1][2 * tx + 1]);
        unsigned R6r = (bby << 1) + ty, C6 = (bbx << 1) + tx;  // 0..63
        *(unsigned*)(wsb + OFF6 + (((size_t)R6r << 6) + C6) * 4) = pack10(v.x, v.y, v.z);
    }
}

// ---------------- sampling (linear level layout) ----------------
__device__ __forceinline__ void tap_off(int lvl, float u, float v,
                                        unsigned& o00, unsigned& o01,
                                        unsigned& o10, unsigned& o11,
                                        float& fx, float& fy) {
    int size = 4096 >> lvl;
    float fs = (float)size;
    float x = fmaf(u, fs, -0.5f);
    float y = fmaf(v, fs, -0.5f);
    float x0f = floorf(x);
    float y0f = floorf(y);
    fx = x - x0f;
    fy = y - y0f;
    int m = size - 1;
    unsigned x0 = (unsigned)(((int)x0f) & m);
    unsigned y0 = (unsigned)(((int)y0f) & m);
    unsigned x1 = (x0 + 1) & (unsigned)m;
    unsigned y1 = (y0 + 1) & (unsigned)m;
    int sh = 12 - lvl;                       // y*size == y << sh
    unsigned r0 = y0 << sh, r1 = y1 << sh;
    o00 = (r0 + x0) << 2;
    o01 = (r0 + x1) << 2;
    o10 = (r1 + x0) << 2;
    o11 = (r1 + x1) << 2;
}

__device__ __forceinline__ void sample_packed(const char* __restrict__ wsb, int lvl,
                                              float u, float v, float wgt,
                                              float& r, float& g, float& b) {
    unsigned o00, o01, o10, o11;
    float fx, fy;
    tap_off(lvl, u, v, o00, o01, o10, o11, fx, fy);
    const char* B = wsb + mip_off_b(lvl);
    unsigned q00 = *(const unsigned*)(B + o00);
    unsigned q01 = *(const unsigned*)(B + o01);
    unsigned q10 = *(const unsigned*)(B + o10);
    unsigned q11 = *(const unsigned*)(B + o11);
    dec_acc(q00, (1.0f - fx) * (1.0f - fy) * wgt, r, g, b);
    dec_acc(q01, fx * (1.0f - fy) * wgt, r, g, b);
    dec_acc(q10, (1.0f - fx) * fy * wgt, r, g, b);
    dec_acc(q11, fx * fy * wgt, r, g, b);
}

// Rare path (lod < 2, ~1.3%): levels 0..1 on the fly from fp32 data.
__device__ void sample_fine(const float* __restrict__ data, int lvl,
                            float u, float v, float wgt,
                            float& r, float& g, float& b) {
    int size = 4096 >> lvl;
    float fs = (float)size;
    float x = u * fs - 0.5f;
    float y = v * fs - 0.5f;
    float x0f = floorf(x);
    float y0f = floorf(y);
    float fx = x - x0f;
    float fy = y - y0f;
    int m = size - 1;
    int x0 = ((int)x0f) & m;
    int y0 = ((int)y0f) & m;
    int x1 = (x0 + 1) & m;
    int y1 = (y0 + 1) & m;
    int k = 1 << lvl;
    float inv = wgt / (float)(k * k);
    float ww[2][2] = {{(1.0f - fx) * (1.0f - fy) * inv, fx * (1.0f - fy) * inv},
                      {(1.0f - fx) * fy * inv, fx * fy * inv}};
    int xs[2] = {x0 << lvl, x1 << lvl};
    int ys[2] = {y0 << lvl, y1 << lvl};
    for (int ty = 0; ty < 2; ++ty)
        for (int tx = 0; tx < 2; ++tx) {
            float tr = 0.0f, tg = 0.0f, tb = 0.0f;
            for (int dy = 0; dy < k; ++dy)
                for (int dx = 0; dx < k; ++dx) {
                    const float* p = data + ((size_t)(ys[ty] + dy) * 4096 + xs[tx] + dx) * 3;
                    tr += p[0]; tg += p[1]; tb += p[2];
                }
            r = fmaf(tr, ww[ty][tx], r);
            g = fmaf(tg, ww[ty][tx], g);
            b = fmaf(tb, ww[ty][tx], b);
        }
}

// Near-never path (lod > 6, P ~ 1e-7): levels 7..8 on the fly from stored L6.
__device__ float4 read_l6(const char* __restrict__ wsb, int xx, int yy) {
    return dec4(*(const unsigned*)(wsb + OFF6 + ((((size_t)yy << 6) + xx) << 2)));
}

__device__ void sample_coarse(const char* __restrict__ wsb, int lvl,
                              float u, float v, float wgt,
                              float& r, float& g, float& b) {
    int size = 4096 >> lvl;          // 32 (l=7) or 16 (l=8)
    float fs = (float)size;
    float x = u * fs - 0.5f;
    float y = v * fs - 0.5f;
    float x0f = floorf(x);
    float y0f = floorf(y);
    float fx = x - x0f;
    float fy = y - y0f;
    int m = size - 1;
    int x0 = ((int)x0f) & m;
    int y0 = ((int)y0f) & m;
    int x1 = (x0 + 1) & m;
    int y1 = (y0 + 1) & m;
    int s = lvl - 6;
    int k = 1 << s;
    float inv = wgt / (float)(k * k);
    float ww[2][2] = {{(1.0f - fx) * (1.0f - fy) * inv, fx * (1.0f - fy) * inv},
                      {(1.0f - fx) * fy * inv, fx * fy * inv}};
    int xs[2] = {x0 << s, x1 << s};
    int ys[2] = {y0 << s, y1 << s};
    for (int ty = 0; ty < 2; ++ty)
        for (int tx = 0; tx < 2; ++tx) {
            float tr = 0.0f, tg = 0.0f, tb = 0.0f;
            for (int dy = 0; dy < k; ++dy)
                for (int dx = 0; dx < k; ++dx) {
                    float4 c = read_l6(wsb, xs[tx] + dx, ys[ty] + dy);
                    tr += c.x; tg += c.y; tb += c.z;
                }
            r = fmaf(tr, ww[ty][tx], r);
            g = fmaf(tg, ww[ty][tx], g);
            b = fmaf(tb, ww[ty][tx], b);
        }
}

__device__ __forceinline__ void sample_any(const float* __restrict__ data,
                                           const char* __restrict__ wsb, int lvl,
                                           float u, float v, float wgt,
                                           float& r, float& g, float& b) {
    if (lvl >= 2) {
        if (lvl <= 6) sample_packed(wsb, lvl, u, v, wgt, r, g, b);
        else sample_coarse(wsb, lvl, u, v, wgt, r, g, b);            // ~never
    } else {
        sample_fine(data, lvl, u, v, wgt, r, g, b);                  // rare
    }
}

__global__ __launch_bounds__(256) void vt_sample(const float* __restrict__ data,
                                                 const char* __restrict__ wsb,
                                                 const float* __restrict__ texc,
                                                 const float* __restrict__ deriv,
                                                 float* __restrict__ out) {
    int p = blockIdx.x * 256 + threadIdx.x;

    float2 uv = ((const float2*)texc)[p];
    float4 dv = ((const float4*)deriv)[p];
    float dudx = dv.x * 4096.0f;
    float dvdx = dv.y * 4096.0f;
    float dudy = dv.z * 4096.0f;
    float dvdy = dv.w * 4096.0f;
    float rho2 = fmaxf(fmaf(dudx, dudx, dvdx * dvdx), fmaf(dudy, dudy, dvdy * dvdy));
    float lod = 0.5f * __log2f(fmaxf(rho2, 1e-20f));
    lod = fminf(fmaxf(lod, 0.0f), 8.0f);

    int l0 = (int)lod;            // trunc == floor for lod >= 0
    float f = lod - (float)l0;
    int l1 = (l0 < 8) ? (l0 + 1) : 8;

    float r = 0.0f, g = 0.0f, b = 0.0f;

    if (__builtin_expect((unsigned)(l0 - 2) <= 3u, 1)) {
        // Fused fast path: l0 in [2,5] -> both levels packed. Compute all 8
        // tap offsets, issue all 8 loads, THEN do the weight math (one wait).
        unsigned a00, a01, a10, a11, b00, b01, b10, b11;
        float fx0, fy0, fx1, fy1;
        const char* B0 = wsb + mip_off_b(l0);
        const char* B1 = wsb + mip_off_b(l1);
        tap_off(l0, uv.x, uv.y, a00, a01, a10, a11, fx0, fy0);
        tap_off(l1, uv.x, uv.y, b00, b01, b10, b11, fx1, fy1);
        unsigned q0 = *(const unsigned*)(B0 + a00);
        unsigned q1 = *(const unsigned*)(B0 + a01);
        unsigned q2 = *(const unsigned*)(B0 + a10);
        unsigned q3 = *(const unsigned*)(B0 + a11);
        unsigned q4 = *(const unsigned*)(B1 + b00);
        unsigned q5 = *(const unsigned*)(B1 + b01);
        unsigned q6 = *(const unsigned*)(B1 + b10);
        unsigned q7 = *(const unsigned*)(B1 + b11);
        float w0 = 1.0f - f;
        dec_acc(q0, (1.0f - fx0) * (1.0f - fy0) * w0, r, g, b);
        dec_acc(q1, fx0 * (1.0f - fy0) * w0, r, g, b);
        dec_acc(q2, (1.0f - fx0) * fy0 * w0, r, g, b);
        dec_acc(q3, fx0 * fy0 * w0, r, g, b);
        dec_acc(q4, (1.0f - fx1) * (1.0f - fy1) * f, r, g, b);
        dec_acc(q5, fx1 * (1.0f - fy1) * f, r, g, b);
        dec_acc(q6, (1.0f - fx1) * fy1 * f, r, g, b);
        dec_acc(q7, fx1 * fy1 * f, r, g, b);
    } else {
        sample_any(data, wsb, l0, uv.x, uv.y, 1.0f - f, r, g, b);
        sample_any(data, wsb, l1, uv.x, uv.y, f, r, g, b);
    }

    float* o = out + (size_t)p * 3;
    o[0] = r;
    o[1] = g;
    o[2] = b;
}

extern "C" void kernel_launch(void* const* d_in, const int* in_sizes, int n_in,
                              void* d_out, int out_size, void* d_ws, size_t ws_size,
                              hipStream_t stream) {
    const float* data  = (const float*)d_in[0];
    const float* texc  = (const float*)d_in[1];
    const float* deriv = (const float*)d_in[2];
    float* out = (float*)d_out;
    char* wsb  = (char*)d_ws;

    mip_l2<<<4096, 256, 0, stream>>>(data, wsb);
    mip_rest<<<1024, 256, 0, stream>>>(wsb);
    vt_sample<<<OUT_N / 256, 256, 0, stream>>>(data, wsb, texc, deriv, out);
}